// Round 3
// baseline (94.556 us; speedup 1.0000x reference)
//
#include <hip/hip_runtime.h>
#include <math.h>

#define AN 4096
#define CN 8
#define FN 64
#define ACN (AN*CN)   // 32768

typedef __attribute__((ext_vector_type(8))) short bf16x8;
typedef __attribute__((ext_vector_type(4))) float f32x4;

// Direct global->LDS DMA, 16B per lane. LDS dest must be wave-uniform
// (HW writes lane l at dest + l*16); global src is per-lane (m104/m173).
#define GLL16(gsrc, ldst) \
    __builtin_amdgcn_global_load_lds( \
        (const __attribute__((address_space(1))) void*)(gsrc), \
        (__attribute__((address_space(3))) void*)(ldst), 16, 0, 0)

__device__ inline unsigned short f2bf(float f) {
    unsigned u = __float_as_uint(f);
    unsigned r = ((u >> 16) & 1) + 0x7FFFu;   // round-to-nearest-even
    return (unsigned short)((u + r) >> 16);
}

// ---------------------------------------------------------------------------
// K1: normalize -> xnb bf16 [c][a][f] (MFMA operand) + inv[a*8+c] fp32
// inverse norms. k3 recomputes x*inv (identical multiply, bit-exact).
// ---------------------------------------------------------------------------
__global__ __launch_bounds__(256) void k1_normalize(const float* __restrict__ x,
                                                    unsigned short* __restrict__ xnb,
                                                    float* __restrict__ inv)
{
    int tid  = threadIdx.x;
    int grp  = tid >> 4;
    int slot = tid & 15;
    #pragma unroll
    for (int s = 0; s < 4; ++s) {
        int V = blockIdx.x * 64 + s * 16 + grp;      // 0..32767 = a*8+c
        const float4 v = *(const float4*)(x + (size_t)V * FN + slot * 4);
        float ss = v.x*v.x + v.y*v.y + v.z*v.z + v.w*v.w;
        ss += __shfl_xor(ss, 1);
        ss += __shfl_xor(ss, 2);
        ss += __shfl_xor(ss, 4);
        ss += __shfl_xor(ss, 8);
        float sc = 1.0f / fmaxf(sqrtf(ss), 1e-6f);
        int a = V >> 3, c = V & 7;
        ushort4 ob;
        ob.x = f2bf(v.x * sc); ob.y = f2bf(v.y * sc);
        ob.z = f2bf(v.z * sc); ob.w = f2bf(v.w * sc);
        *(ushort4*)(xnb + ((size_t)c * AN + a) * FN + slot * 4) = ob;
        if (slot == 0) inv[V] = sc;
    }
}

// ---------------------------------------------------------------------------
// K2: MFMA sim + in-register packed argmax.
// Grid 512 = 8 channels x 32 row-tiles x 2 col-halves. 256 threads = 4 waves,
// each wave owns ALL 128 rows x 32 cols (1x4 layout): B-frag LDS reads halve
// vs the 2x2 layout (4 ds_read_b128/wave/iter), A-frags register-resident
// (afr[8][2]).
// Staging: global_load_lds 16B DMA with PRE-SWIZZLED global source — the XOR
// (r&7) chunk swizzle permutes 16B chunks within a row's 128B line, so the
// swizzled source hits the same cache lines; LDS dest stays linear (m173).
// ds_read of B frags applies the same XOR -> <=2-way bank alias (free, m136).
// Packed argmax: acc init 2.0 (s'=2+sim in [1,3]); packed=(bits&~0xFFF)|col;
// float-max == lexicographic (quantized s', col). Diagonal excluded by zeroing
// the packed candidate on the diag fragment (wave-uniform branch).
// ---------------------------------------------------------------------------
__global__ __launch_bounds__(256, 2) void k2_argmax(const unsigned short* __restrict__ xnb,
                                                    unsigned int* __restrict__ pP)
{
    __shared__ uint4 lds4[3 * 1024];   // At [0,1024) | Bt0 [1024,2048) | Bt1 [2048,3072)

    int blk  = blockIdx.x;
    int half = blk & 1;
    int rt   = (blk >> 1) & 31;
    int c    = blk >> 6;
    int a0   = rt * 128;
    int b0base = half * 2048;

    const char* __restrict__ Xc = (const char*)(xnb + (size_t)c * AN * FN); // row r at byte r*128

    int tid  = threadIdx.x;
    int lane = tid & 63;
    int w    = tid >> 6;      // wave 0..3 -> col group w*32
    int l15  = lane & 15;
    int quad = lane >> 4;

    // staging geometry (per wave-instruction): LDS chunk ci = base64 + lane,
    // row = ci>>3, slot = ci&7, global chunk = slot ^ (row&7).
    int srow  = lane >> 3;    // row offset within the 8-row group of this lane
    int sslot = lane & 7;

    // ---- stage A tile + B tile 0 (8 DMA issues per thread) ----
    #pragma unroll
    for (int s = 0; s < 4; ++s) {
        int base = (w * 4 + s) * 64;           // chunk base (wave-uniform)
        int row  = (base >> 3) + srow;         // 8 rows per wave-instruction
        int gch  = sslot ^ (row & 7);
        size_t gb = (size_t)row * 128 + (size_t)gch * 16;
        GLL16(Xc + (size_t)(a0) * 128 + gb,      lds4 + base);
        GLL16(Xc + (size_t)(b0base) * 128 + gb,  lds4 + 1024 + base);
    }
    __syncthreads();

    // ---- A fragments into registers (all 128 rows, loop-invariant) ----
    bf16x8 afr[8][2];
    #pragma unroll
    for (int mi = 0; mi < 8; ++mi)
        #pragma unroll
        for (int ks = 0; ks < 2; ++ks) {
            int r  = mi * 16 + l15;
            int ch = (ks * 4 + quad) ^ (r & 7);
            afr[mi][ks] = ((const bf16x8*)lds4)[r * 8 + ch];
        }

    float bestp[32];
    #pragma unroll
    for (int i = 0; i < 32; ++i) bestp[i] = 0.0f;

    const f32x4 two = {2.0f, 2.0f, 2.0f, 2.0f};

    for (int it = 0; it < 16; ++it) {
        int cur = it & 1;

        // ---- issue next-tile DMA into the other buffer (flies under MFMA) ----
        if (it < 15) {
            int g0 = b0base + (it + 1) * 128;
            #pragma unroll
            for (int s = 0; s < 4; ++s) {
                int base = (w * 4 + s) * 64;
                int row  = (base >> 3) + srow;
                int gch  = sslot ^ (row & 7);
                GLL16(Xc + (size_t)(g0 + row) * 128 + (size_t)gch * 16,
                      lds4 + 1024 + (cur ^ 1) * 1024 + base);
            }
        }

        // ---- MFMA on buffer cur ----
        f32x4 acc[8][2];
        const bf16x8* bt = (const bf16x8*)(lds4 + 1024 + cur * 1024);
        #pragma unroll
        for (int ks = 0; ks < 2; ++ks) {
            #pragma unroll
            for (int ni = 0; ni < 2; ++ni) {
                int r  = w * 32 + ni * 16 + l15;
                int ch = (ks * 4 + quad) ^ (r & 7);
                bf16x8 bfr = bt[r * 8 + ch];
                #pragma unroll
                for (int mi = 0; mi < 8; ++mi)
                    acc[mi][ni] = __builtin_amdgcn_mfma_f32_16x16x32_bf16(
                        afr[mi][ks], bfr, (ks == 0) ? two : acc[mi][ni], 0, 0, 0);
            }
        }

        // ---- packed argmax update (gather-2 then max3-reduce) ----
        int colblk = b0base + it * 128 + w * 32;
        #pragma unroll
        for (int mi = 0; mi < 8; ++mi) {
            int rfrag = a0 + mi * 16;
            #pragma unroll
            for (int r = 0; r < 4; ++r) {
                unsigned p0 = (__float_as_uint(acc[mi][0][r]) & 0xFFFFF000u)
                            | (unsigned)(colblk + l15);
                unsigned p1 = (__float_as_uint(acc[mi][1][r]) & 0xFFFFF000u)
                            | (unsigned)(colblk + 16 + l15);
                float c0 = __uint_as_float(p0);
                float c1 = __uint_as_float(p1);
                if (rfrag == colblk) {                    // wave-uniform
                    if (l15 == quad * 4 + r) c0 = 0.0f;
                }
                if (rfrag == colblk + 16) {               // wave-uniform
                    if (l15 == quad * 4 + r) c1 = 0.0f;
                }
                int bi = mi * 4 + r;
                bestp[bi] = fmaxf(fmaxf(c0, c1), bestp[bi]);
            }
        }

        __syncthreads();   // drains the DMA (vmcnt 0) + guards buffer reuse
    }

    // ---- reduce across the 16 column-lanes ----
    #pragma unroll
    for (int i = 0; i < 32; ++i) {
        float v = bestp[i];
        v = fmaxf(v, __shfl_xor(v, 1));
        v = fmaxf(v, __shfl_xor(v, 2));
        v = fmaxf(v, __shfl_xor(v, 4));
        v = fmaxf(v, __shfl_xor(v, 8));
        bestp[i] = v;
    }
    __syncthreads();                    // At region now reusable
    float* red = (float*)lds4;          // red[w][128]
    if (l15 == 0) {
        #pragma unroll
        for (int mi = 0; mi < 8; ++mi)
            #pragma unroll
            for (int r = 0; r < 4; ++r)
                red[w * 128 + mi * 16 + quad * 4 + r] = bestp[mi * 4 + r];
    }
    __syncthreads();
    if (tid < 128) {
        float p = fmaxf(fmaxf(red[tid], red[128 + tid]),
                        fmaxf(red[256 + tid], red[384 + tid]));
        int a = a0 + tid;
        pP[(size_t)half * ACN + (size_t)a * CN + c] = __float_as_uint(p);
    }
}

// ---------------------------------------------------------------------------
// K3: merge halves, unpack index, exact fp32 distance (x*inv recomputes the
// normalized values with identical multiplies) + log, block-reduce.
// ---------------------------------------------------------------------------
__global__ __launch_bounds__(256) void k3_dist(const float* __restrict__ x,
                                               const float* __restrict__ inv,
                                               const unsigned int* __restrict__ pP,
                                               float* __restrict__ partials)
{
    int tid = threadIdx.x;
    int id = blockIdx.x * 256 + tid;            // a*8 + c
    float p0 = __uint_as_float(pP[id]);
    float p1 = __uint_as_float(pP[ACN + id]);
    unsigned pm = __float_as_uint(fmaxf(p0, p1));
    int m = (int)(pm & 0xFFFu);
    int c = id & 7;
    int idb = m * CN + c;
    float sa = inv[id];
    float sb = inv[idb];
    const float* xa = x + (size_t)id  * FN;
    const float* xb = x + (size_t)idb * FN;
    float ss = 0.0f;
    #pragma unroll
    for (int q = 0; q < 16; ++q) {
        float4 va = *(const float4*)(xa + 4 * q);
        float4 vb = *(const float4*)(xb + 4 * q);
        float d0 = va.x * sa - vb.x * sb + 1e-6f;
        float d1 = va.y * sa - vb.y * sb + 1e-6f;
        float d2 = va.z * sa - vb.z * sb + 1e-6f;
        float d3 = va.w * sa - vb.w * sb + 1e-6f;
        ss += d0*d0 + d1*d1 + d2*d2 + d3*d3;
    }
    float val = logf(sqrtf(ss) + 1e-6f);

    float t = val;
    #pragma unroll
    for (int off = 32; off > 0; off >>= 1) t += __shfl_down(t, off);
    __shared__ float ws4[4];
    if ((tid & 63) == 0) ws4[tid >> 6] = t;
    __syncthreads();
    if (tid == 0)
        partials[blockIdx.x] = ws4[0] + ws4[1] + ws4[2] + ws4[3];
}

// ---------------------------------------------------------------------------
// K4: out = -sum(partials)/32768
// ---------------------------------------------------------------------------
__global__ __launch_bounds__(64) void k4_final(const float* __restrict__ partials,
                                               float* __restrict__ out)
{
    int t = threadIdx.x;
    float v = partials[t] + partials[t + 64];
    #pragma unroll
    for (int off = 32; off > 0; off >>= 1) v += __shfl_down(v, off);
    if (t == 0) out[0] = -v / (float)ACN;
}

extern "C" void kernel_launch(void* const* d_in, const int* in_sizes, int n_in,
                              void* d_out, int out_size, void* d_ws, size_t ws_size,
                              hipStream_t stream)
{
    const float* x = (const float*)d_in[0];
    unsigned short* xnb = (unsigned short*)d_ws;               // 4 MB bf16 [c][a][f]
    float* inv = (float*)(xnb + (size_t)AN * CN * FN);         // 128 KB inverse norms
    unsigned int* pP = (unsigned int*)(inv + ACN);             // 256 KB packed argmax
    float* partials = (float*)(pP + 2 * ACN);                  // 512 B

    k1_normalize<<<512, 256, 0, stream>>>(x, xnb, inv);
    k2_argmax  <<<512, 256, 0, stream>>>(xnb, pP);
    k3_dist    <<<128, 256, 0, stream>>>(x, inv, pP, partials);
    k4_final   <<<1, 64, 0, stream>>>(partials, (float*)d_out);
}

// Round 4
// 94.256 us; speedup vs baseline: 1.0032x; 1.0032x over previous
//
#include <hip/hip_runtime.h>
#include <math.h>

#define AN 4096
#define CN 8
#define FN 64
#define ACN (AN*CN)   // 32768

typedef __attribute__((ext_vector_type(8))) short bf16x8;
typedef __attribute__((ext_vector_type(4))) float f32x4;

// Direct global->LDS DMA, 16B per lane. LDS dest is wave-uniform base
// (HW writes lane l at dest + l*16); global src is per-lane (m104/m173).
#define GLL16(gsrc, ldst) \
    __builtin_amdgcn_global_load_lds( \
        (const __attribute__((address_space(1))) void*)(gsrc), \
        (__attribute__((address_space(3))) void*)(ldst), 16, 0, 0)

__device__ inline unsigned short f2bf(float f) {
    unsigned u = __float_as_uint(f);
    unsigned r = ((u >> 16) & 1) + 0x7FFFu;   // round-to-nearest-even
    return (unsigned short)((u + r) >> 16);
}

// ---------------------------------------------------------------------------
// K1: normalize -> xnb bf16 [c][a][f] (MFMA operand) + inv[a*8+c] fp32
// inverse norms. k3 recomputes x*inv (identical multiply, bit-exact).
// ---------------------------------------------------------------------------
__global__ __launch_bounds__(256) void k1_normalize(const float* __restrict__ x,
                                                    unsigned short* __restrict__ xnb,
                                                    float* __restrict__ inv)
{
    int tid  = threadIdx.x;
    int grp  = tid >> 4;
    int slot = tid & 15;
    #pragma unroll
    for (int s = 0; s < 4; ++s) {
        int V = blockIdx.x * 64 + s * 16 + grp;      // 0..32767 = a*8+c
        const float4 v = *(const float4*)(x + (size_t)V * FN + slot * 4);
        float ss = v.x*v.x + v.y*v.y + v.z*v.z + v.w*v.w;
        ss += __shfl_xor(ss, 1);
        ss += __shfl_xor(ss, 2);
        ss += __shfl_xor(ss, 4);
        ss += __shfl_xor(ss, 8);
        float sc = 1.0f / fmaxf(sqrtf(ss), 1e-6f);
        int a = V >> 3, c = V & 7;
        ushort4 ob;
        ob.x = f2bf(v.x * sc); ob.y = f2bf(v.y * sc);
        ob.z = f2bf(v.z * sc); ob.w = f2bf(v.w * sc);
        *(ushort4*)(xnb + ((size_t)c * AN + a) * FN + slot * 4) = ob;
        if (slot == 0) inv[V] = sc;
    }
}

// ---------------------------------------------------------------------------
// K2: MFMA sim + in-register packed argmax — BARRIER-FREE main loop.
// Grid 512 = 8 channels x 32 row-tiles x 2 col-halves. 4 waves, each owns
// ALL 128 rows x 32 cols. KEY: B staging is wave-private (wave w stages and
// reads exactly LDS chunks [w*256,(w+1)*256)), so buffer reuse needs only the
// wave's own s_waitcnt vmcnt(N) — no __syncthreads in the 16-iter loop.
// Triple-buffered B, prefetch depth 2, counted vmcnt(8) (never 0 in-loop):
// T3+T4. setprio(1) around ds_read+MFMA cluster: T5 (waves are decoupled ->
// role diversity exists). Only the A tile (read by all waves) needs the one
// prologue barrier.
// Staging uses global_load_lds with PRE-SWIZZLED global source (chunk XOR
// (row&7) permutes 16B chunks within a row's 128B line; same cache lines).
// ds_read applies the same XOR -> <=2-way bank alias (free, m136).
// Packed argmax: acc init 2.0 (s'=2+sim in [1,3]); packed=(bits&~0xFFF)|col;
// float-max == lexicographic (quantized s', col). Diagonal excluded by
// zeroing the packed candidate on the diag fragment (wave-uniform branch).
// All MFMA/pack ops byte-identical to round 2/3 -> bit-exact result.
// ---------------------------------------------------------------------------
__global__ __launch_bounds__(256, 2) void k2_argmax(const unsigned short* __restrict__ xnb,
                                                    unsigned int* __restrict__ pP)
{
    __shared__ uint4 lds4[4 * 1024];   // At | B0 | B1 | B2 (16KB each)

    int blk  = blockIdx.x;
    int half = blk & 1;
    int rt   = (blk >> 1) & 31;
    int c    = blk >> 6;
    int a0   = rt * 128;
    int b0base = half * 2048;

    const char* __restrict__ Xc = (const char*)(xnb + (size_t)c * AN * FN); // row r at byte r*128

    int tid  = threadIdx.x;
    int lane = tid & 63;
    int w    = tid >> 6;      // wave 0..3 -> col group w*32
    int l15  = lane & 15;
    int quad = lane >> 4;

    // staging geometry: LDS chunk ci = base64 + lane, row = ci>>3, slot = ci&7,
    // global chunk = slot ^ (row&7).
    int srow  = lane >> 3;
    int sslot = lane & 7;

    // ---- prologue: stage A + B0 + B1 (12 DMA issues per wave) ----
    #pragma unroll
    for (int s = 0; s < 4; ++s) {
        int base = (w * 4 + s) * 64;           // wave-uniform chunk base
        int row  = (base >> 3) + srow;
        int gch  = sslot ^ (row & 7);
        size_t gb = (size_t)row * 128 + (size_t)gch * 16;
        GLL16(Xc + (size_t)a0 * 128 + gb,              lds4 + base);         // A
        GLL16(Xc + (size_t)b0base * 128 + gb,          lds4 + 1024 + base);  // B0
        GLL16(Xc + (size_t)(b0base + 128) * 128 + gb,  lds4 + 2048 + base);  // B1
    }
    __syncthreads();   // drain + all waves' A visible

    // ---- A fragments into registers (all 128 rows, loop-invariant) ----
    bf16x8 afr[8][2];
    #pragma unroll
    for (int mi = 0; mi < 8; ++mi)
        #pragma unroll
        for (int ks = 0; ks < 2; ++ks) {
            int r  = mi * 16 + l15;
            int ch = (ks * 4 + quad) ^ (r & 7);
            afr[mi][ks] = ((const bf16x8*)lds4)[r * 8 + ch];
        }

    float bestp[32];
    #pragma unroll
    for (int i = 0; i < 32; ++i) bestp[i] = 0.0f;

    const f32x4 two = {2.0f, 2.0f, 2.0f, 2.0f};

    uint4* bc = lds4 + 1024;   // tile t
    uint4* bn = lds4 + 2048;   // tile t+1 (in flight or landed)
    uint4* bt2 = lds4 + 3072;  // tile t+2 (issue target)

    for (int it = 0; it < 16; ++it) {
        // ---- issue DMA for tile it+2 into bt2 (wave-private region) ----
        if (it < 14) {
            int g0 = b0base + (it + 2) * 128;
            #pragma unroll
            for (int s = 0; s < 4; ++s) {
                int base = (w * 4 + s) * 64;
                int row  = (base >> 3) + srow;
                int gch  = sslot ^ (row & 7);
                GLL16(Xc + (size_t)(g0 + row) * 128 + (size_t)gch * 16,
                      bt2 + base);
            }
        }

        // ---- counted wait: tile it landed; it+1/it+2 stay in flight ----
        if (it < 14)       { asm volatile("s_waitcnt vmcnt(8)" ::: "memory"); }
        else if (it == 14) { asm volatile("s_waitcnt vmcnt(4)" ::: "memory"); }
        else               { asm volatile("s_waitcnt vmcnt(0)" ::: "memory"); }
        __builtin_amdgcn_sched_barrier(0);

        // ---- MFMA on tile it (reads only this wave's staged chunks) ----
        f32x4 acc[8][2];
        __builtin_amdgcn_s_setprio(1);
        #pragma unroll
        for (int ks = 0; ks < 2; ++ks) {
            #pragma unroll
            for (int ni = 0; ni < 2; ++ni) {
                int r  = w * 32 + ni * 16 + l15;
                int ch = (ks * 4 + quad) ^ (r & 7);
                bf16x8 bfr = ((const bf16x8*)bc)[r * 8 + ch];
                #pragma unroll
                for (int mi = 0; mi < 8; ++mi)
                    acc[mi][ni] = __builtin_amdgcn_mfma_f32_16x16x32_bf16(
                        afr[mi][ks], bfr, (ks == 0) ? two : acc[mi][ni], 0, 0, 0);
            }
        }
        __builtin_amdgcn_s_setprio(0);

        // ---- packed argmax update ----
        int colblk = b0base + it * 128 + w * 32;
        #pragma unroll
        for (int mi = 0; mi < 8; ++mi) {
            int rfrag = a0 + mi * 16;
            #pragma unroll
            for (int r = 0; r < 4; ++r) {
                unsigned p0 = (__float_as_uint(acc[mi][0][r]) & 0xFFFFF000u)
                            | (unsigned)(colblk + l15);
                unsigned p1 = (__float_as_uint(acc[mi][1][r]) & 0xFFFFF000u)
                            | (unsigned)(colblk + 16 + l15);
                float c0 = __uint_as_float(p0);
                float c1 = __uint_as_float(p1);
                if (rfrag == colblk) {                    // wave-uniform
                    if (l15 == quad * 4 + r) c0 = 0.0f;
                }
                if (rfrag == colblk + 16) {               // wave-uniform
                    if (l15 == quad * 4 + r) c1 = 0.0f;
                }
                int bi = mi * 4 + r;
                bestp[bi] = fmaxf(fmaxf(c0, c1), bestp[bi]);
            }
        }

        // ---- rotate buffers (no sync needed: wave-private) ----
        uint4* tmp = bc; bc = bn; bn = bt2; bt2 = tmp;
    }

    // ---- reduce across the 16 column-lanes ----
    #pragma unroll
    for (int i = 0; i < 32; ++i) {
        float v = bestp[i];
        v = fmaxf(v, __shfl_xor(v, 1));
        v = fmaxf(v, __shfl_xor(v, 2));
        v = fmaxf(v, __shfl_xor(v, 4));
        v = fmaxf(v, __shfl_xor(v, 8));
        bestp[i] = v;
    }
    __syncthreads();                    // all waves done; A region reusable
    float* red = (float*)lds4;          // red[w][128]
    if (l15 == 0) {
        #pragma unroll
        for (int mi = 0; mi < 8; ++mi)
            #pragma unroll
            for (int r = 0; r < 4; ++r)
                red[w * 128 + mi * 16 + quad * 4 + r] = bestp[mi * 4 + r];
    }
    __syncthreads();
    if (tid < 128) {
        float p = fmaxf(fmaxf(red[tid], red[128 + tid]),
                        fmaxf(red[256 + tid], red[384 + tid]));
        int a = a0 + tid;
        pP[(size_t)half * ACN + (size_t)a * CN + c] = __float_as_uint(p);
    }
}

// ---------------------------------------------------------------------------
// K3: merge halves, unpack index, exact fp32 distance (x*inv recomputes the
// normalized values with identical multiplies) + log, block-reduce.
// ---------------------------------------------------------------------------
__global__ __launch_bounds__(256) void k3_dist(const float* __restrict__ x,
                                               const float* __restrict__ inv,
                                               const unsigned int* __restrict__ pP,
                                               float* __restrict__ partials)
{
    int tid = threadIdx.x;
    int id = blockIdx.x * 256 + tid;            // a*8 + c
    float p0 = __uint_as_float(pP[id]);
    float p1 = __uint_as_float(pP[ACN + id]);
    unsigned pm = __float_as_uint(fmaxf(p0, p1));
    int m = (int)(pm & 0xFFFu);
    int c = id & 7;
    int idb = m * CN + c;
    float sa = inv[id];
    float sb = inv[idb];
    const float* xa = x + (size_t)id  * FN;
    const float* xb = x + (size_t)idb * FN;
    float ss = 0.0f;
    #pragma unroll
    for (int q = 0; q < 16; ++q) {
        float4 va = *(const float4*)(xa + 4 * q);
        float4 vb = *(const float4*)(xb + 4 * q);
        float d0 = va.x * sa - vb.x * sb + 1e-6f;
        float d1 = va.y * sa - vb.y * sb + 1e-6f;
        float d2 = va.z * sa - vb.z * sb + 1e-6f;
        float d3 = va.w * sa - vb.w * sb + 1e-6f;
        ss += d0*d0 + d1*d1 + d2*d2 + d3*d3;
    }
    float val = logf(sqrtf(ss) + 1e-6f);

    float t = val;
    #pragma unroll
    for (int off = 32; off > 0; off >>= 1) t += __shfl_down(t, off);
    __shared__ float ws4[4];
    if ((tid & 63) == 0) ws4[tid >> 6] = t;
    __syncthreads();
    if (tid == 0)
        partials[blockIdx.x] = ws4[0] + ws4[1] + ws4[2] + ws4[3];
}

// ---------------------------------------------------------------------------
// K4: out = -sum(partials)/32768
// ---------------------------------------------------------------------------
__global__ __launch_bounds__(64) void k4_final(const float* __restrict__ partials,
                                               float* __restrict__ out)
{
    int t = threadIdx.x;
    float v = partials[t] + partials[t + 64];
    #pragma unroll
    for (int off = 32; off > 0; off >>= 1) v += __shfl_down(v, off);
    if (t == 0) out[0] = -v / (float)ACN;
}

extern "C" void kernel_launch(void* const* d_in, const int* in_sizes, int n_in,
                              void* d_out, int out_size, void* d_ws, size_t ws_size,
                              hipStream_t stream)
{
    const float* x = (const float*)d_in[0];
    unsigned short* xnb = (unsigned short*)d_ws;               // 4 MB bf16 [c][a][f]
    float* inv = (float*)(xnb + (size_t)AN * CN * FN);         // 128 KB inverse norms
    unsigned int* pP = (unsigned int*)(inv + ACN);             // 256 KB packed argmax
    float* partials = (float*)(pP + 2 * ACN);                  // 512 B

    k1_normalize<<<512, 256, 0, stream>>>(x, xnb, inv);
    k2_argmax  <<<512, 256, 0, stream>>>(xnb, pP);
    k3_dist    <<<128, 256, 0, stream>>>(x, inv, pP, partials);
    k4_final   <<<1, 64, 0, stream>>>(partials, (float*)d_out);
}